// Round 2
// baseline (433.204 us; speedup 1.0000x reference)
//
#include <hip/hip_runtime.h>
#include <hip/hip_bf16.h>
#include <math.h>

#define N_PTS 4096
#define BATCH 4

// ---------------------------------------------------------------------------
// maxd2 init (avoid memset-node ambiguity; deterministic each call)
// ---------------------------------------------------------------------------
__global__ void init_maxd2_kernel(unsigned int* p) {
    if (threadIdx.x < BATCH) p[threadIdx.x] = 0u;
}

// ---------------------------------------------------------------------------
// Per-batch max pairwise squared distance.
// Grid: (N/64, B), 256 threads: 64 i-points x 4 j-quadrants.
// xyz[b] staged in LDS (48 KB). d2 >= 0 so float-as-uint atomicMax is ordered.
// ---------------------------------------------------------------------------
__global__ __launch_bounds__(256) void radius_max_kernel(
    const float* __restrict__ xyz, unsigned int* __restrict__ maxd2)
{
    const int b = blockIdx.y;
    __shared__ float sx[N_PTS], sy[N_PTS], sz[N_PTS];
    const float* xb = xyz + (size_t)b * N_PTS * 3;
    for (int idx = threadIdx.x; idx < N_PTS; idx += 256) {
        sx[idx] = xb[idx * 3 + 0];
        sy[idx] = xb[idx * 3 + 1];
        sz[idx] = xb[idx * 3 + 2];
    }
    __syncthreads();
    const int il = threadIdx.x & 63;   // lane within wave = i index
    const int jq = threadIdx.x >> 6;   // wave = j quadrant (uniform j per wave -> LDS broadcast)
    const int i = blockIdx.x * 64 + il;
    const float xi = sx[i], yi = sy[i], zi = sz[i];
    float m = 0.f;
    const int j0 = jq * (N_PTS / 4);
    for (int j = j0; j < j0 + N_PTS / 4; ++j) {
        float dx = xi - sx[j], dy = yi - sy[j], dz = zi - sz[j];
        float d2 = dx * dx + dy * dy + dz * dz;
        m = fmaxf(m, d2);
    }
    for (int off = 32; off >= 1; off >>= 1) m = fmaxf(m, __shfl_down(m, off));
    __shared__ float wred[4];
    if ((threadIdx.x & 63) == 0) wred[threadIdx.x >> 6] = m;
    __syncthreads();
    if (threadIdx.x == 0) {
        float mm = fmaxf(fmaxf(wred[0], wred[1]), fmaxf(wred[2], wred[3]));
        atomicMax(&maxd2[b], __float_as_uint(mm));
    }
}

// ---------------------------------------------------------------------------
// Eigen-feature branch: neighbor-mask accumulation (cnt, S1, S2), covariance,
// closed-form symmetric 3x3 eigvalsh (ascending), fused 3->4->4 ED MLP.
// Writes h3 into z_in channels 160..163.  Grid: (N/64, B), 256 threads.
// ---------------------------------------------------------------------------
__global__ __launch_bounds__(256) void eigen_kernel(
    const float* __restrict__ xyz, const unsigned int* __restrict__ maxd2,
    const float* __restrict__ ew1, const float* __restrict__ eb1,
    const float* __restrict__ ew2, const float* __restrict__ eb2,
    float* __restrict__ zin)
{
    const int b = blockIdx.y;
    __shared__ float sx[N_PTS], sy[N_PTS], sz[N_PTS];
    __shared__ float red[4][64][10];
    const float* xb = xyz + (size_t)b * N_PTS * 3;
    for (int idx = threadIdx.x; idx < N_PTS; idx += 256) {
        sx[idx] = xb[idx * 3 + 0];
        sy[idx] = xb[idx * 3 + 1];
        sz[idx] = xb[idx * 3 + 2];
    }
    __syncthreads();
    const int il = threadIdx.x & 63;
    const int jq = threadIdx.x >> 6;
    const int i = blockIdx.x * 64 + il;
    const float xi = sx[i], yi = sy[i], zi = sz[i];
    const float md2 = __uint_as_float(maxd2[b]);
    const float radius = 0.1f * sqrtf(md2);
    const float r2 = radius * radius;

    float acc[10] = {0.f, 0.f, 0.f, 0.f, 0.f, 0.f, 0.f, 0.f, 0.f, 0.f};
    const int j0 = jq * (N_PTS / 4);
    for (int j = j0; j < j0 + N_PTS / 4; ++j) {
        float xj = sx[j], yj = sy[j], zj = sz[j];
        float dx = xi - xj, dy = yi - yj, dz = zi - zj;
        float d2 = dx * dx + dy * dy + dz * dz;
        if (d2 < r2 && j != i) {
            acc[0] += 1.f;
            acc[1] += xj;      acc[2] += yj;      acc[3] += zj;
            acc[4] += xj * xj; acc[5] += xj * yj; acc[6] += xj * zj;
            acc[7] += yj * yj; acc[8] += yj * zj; acc[9] += zj * zj;
        }
    }
    #pragma unroll
    for (int q = 0; q < 10; ++q) red[jq][il][q] = acc[q];
    __syncthreads();

    if (threadIdx.x < 64) {
        double s[10];
        #pragma unroll
        for (int q = 0; q < 10; ++q)
            s[q] = (double)red[0][il][q] + (double)red[1][il][q] +
                   (double)red[2][il][q] + (double)red[3][il][q];
        double cnt = s[0];
        double denom = fmax(cnt, 1.0);
        double mx = s[1] / denom, my = s[2] / denom, mz = s[3] / denom;
        const double invN = 1.0 / (double)N_PTS;
        double c00 = (s[4] - cnt * mx * mx) * invN;
        double c01 = (s[5] - cnt * mx * my) * invN;
        double c02 = (s[6] - cnt * mx * mz) * invN;
        double c11 = (s[7] - cnt * my * my) * invN;
        double c12 = (s[8] - cnt * my * mz) * invN;
        double c22 = (s[9] - cnt * mz * mz) * invN;

        // Cardano / Smith closed-form eigvalsh for symmetric 3x3, ascending.
        double qm = (c00 + c11 + c22) / 3.0;
        double p1 = c01 * c01 + c02 * c02 + c12 * c12;
        double a0 = c00 - qm, a1 = c11 - qm, a2 = c22 - qm;
        double p2 = a0 * a0 + a1 * a1 + a2 * a2 + 2.0 * p1;
        double e_lo, e_mid, e_hi;
        if (p2 < 1e-32) {
            e_lo = e_mid = e_hi = qm;
        } else {
            double p = sqrt(p2 / 6.0);
            double inv = 1.0 / p;
            double b00 = a0 * inv, b11 = a1 * inv, b22 = a2 * inv;
            double b01 = c01 * inv, b02 = c02 * inv, b12 = c12 * inv;
            double detB = b00 * (b11 * b22 - b12 * b12)
                        - b01 * (b01 * b22 - b12 * b02)
                        + b02 * (b01 * b12 - b11 * b02);
            double r = 0.5 * detB;
            r = fmin(1.0, fmax(-1.0, r));
            double phi = acos(r) / 3.0;
            double two_p = 2.0 * p;
            e_hi = qm + two_p * cos(phi);
            e_lo = qm + two_p * cos(phi + 2.0943951023931953);  // +2*pi/3
            e_mid = 3.0 * qm - e_hi - e_lo;
        }
        float e0 = (float)e_lo, e1 = (float)e_mid, e2 = (float)e_hi;

        // ED MLP: relu(eig @ ed_w1^T + b1) @ ed_w2^T + b2   (no relu on 2nd)
        float t[4];
        #pragma unroll
        for (int o = 0; o < 4; ++o)
            t[o] = fmaxf(e0 * ew1[o * 3 + 0] + e1 * ew1[o * 3 + 1] +
                         e2 * ew1[o * 3 + 2] + eb1[o], 0.f);
        #pragma unroll
        for (int o = 0; o < 4; ++o) {
            float h = t[0] * ew2[o * 4 + 0] + t[1] * ew2[o * 4 + 1] +
                      t[2] * ew2[o * 4 + 2] + t[3] * ew2[o * 4 + 3] + eb2[o];
            zin[((size_t)b * 164 + 160 + o) * N_PTS + i] = h;
        }
    }
}

// ---------------------------------------------------------------------------
// h1 [B,128,N] -> z_in channels 0..127 (float4 copy)
// ---------------------------------------------------------------------------
__global__ __launch_bounds__(256) void copy_h1_kernel(
    const float* __restrict__ h1, float* __restrict__ zin)
{
    size_t idx = (size_t)blockIdx.x * 256 + threadIdx.x;
    const size_t total = (size_t)BATCH * 128 * N_PTS / 4;
    if (idx >= total) return;
    size_t e = idx * 4;
    size_t n = e & (N_PTS - 1);
    size_t c = (e >> 12) & 127;
    size_t b = e >> 19;
    float4 v = *reinterpret_cast<const float4*>(&h1[e]);
    *reinterpret_cast<float4*>(&zin[((b * 164 + c) << 12) + n]) = v;
}

// ---------------------------------------------------------------------------
// xyz passthrough -> f32 output head (output dtype is float32)
// ---------------------------------------------------------------------------
__global__ __launch_bounds__(256) void xyz_out_kernel(
    const float* __restrict__ xyz, float* __restrict__ out)
{
    int idx = blockIdx.x * 256 + threadIdx.x;
    if (idx < BATCH * N_PTS * 3) out[idx] = xyz[idx];
}

// ---------------------------------------------------------------------------
// Fused 1x1 conv + inference BN + ReLU as tiled f32 GEMM.
//   Y[b,m,n] = relu((sum_k W[m,k] X[b,k,n] + bias[m]) * scale[m] + shift[m])
// Tile 64x64, microtile 4x4, BK=16.  Grid: (N/64, ceil(M/64), B).
// Y pointer is pre-offset to this layer's channel 0; y_batch_stride covers
// interleaved destinations (e.g. z_in with 164 channels).
// ---------------------------------------------------------------------------
__global__ __launch_bounds__(256) void conv_bn_relu_gemm(
    const float* __restrict__ W, const float* __restrict__ X,
    const float* __restrict__ bias, const float* __restrict__ scale,
    const float* __restrict__ shift, float* __restrict__ Y,
    int M, int K, size_t y_batch_stride)
{
    constexpr int BM = 64, BN = 64, BK = 16;
    const int b = blockIdx.z;
    const float* Xb = X + (size_t)b * K * N_PTS;
    __shared__ float Wt[BK][BM + 4];  // transposed: Wt[k][m]; +4 keeps float4 alignment
    __shared__ float Xt[BK][BN + 4];
    const int tid = threadIdx.x;
    const int tx = tid & 15, ty = tid >> 4;
    const int m0 = blockIdx.y * BM, n0 = blockIdx.x * BN;
    float acc[4][4] = {};

    for (int k0 = 0; k0 < K; k0 += BK) {
        {   // stage W tile: thread -> (m = tid/4, 4 consecutive k). K%4==0 always.
            int m = tid >> 2, kq = (tid & 3) * 4;
            float4 v = {0.f, 0.f, 0.f, 0.f};
            if (m0 + m < M && k0 + kq < K)
                v = *reinterpret_cast<const float4*>(&W[(size_t)(m0 + m) * K + k0 + kq]);
            Wt[kq + 0][m] = v.x; Wt[kq + 1][m] = v.y;
            Wt[kq + 2][m] = v.z; Wt[kq + 3][m] = v.w;
        }
        {   // stage X tile: thread -> (k = tid/16, 4 consecutive n). Coalesced.
            int k = tid >> 4, nq = (tid & 15) * 4;
            float4 v = {0.f, 0.f, 0.f, 0.f};
            if (k0 + k < K)
                v = *reinterpret_cast<const float4*>(&Xb[(size_t)(k0 + k) * N_PTS + n0 + nq]);
            *reinterpret_cast<float4*>(&Xt[k][nq]) = v;
        }
        __syncthreads();
        #pragma unroll
        for (int kk = 0; kk < BK; ++kk) {
            float4 a  = *reinterpret_cast<const float4*>(&Wt[kk][ty * 4]);
            float4 bb = *reinterpret_cast<const float4*>(&Xt[kk][tx * 4]);
            float av[4] = {a.x, a.y, a.z, a.w};
            float bv[4] = {bb.x, bb.y, bb.z, bb.w};
            #pragma unroll
            for (int ii = 0; ii < 4; ++ii)
                #pragma unroll
                for (int jj = 0; jj < 4; ++jj)
                    acc[ii][jj] = fmaf(av[ii], bv[jj], acc[ii][jj]);
        }
        __syncthreads();
    }

    #pragma unroll
    for (int ii = 0; ii < 4; ++ii) {
        int m = m0 + ty * 4 + ii;
        if (m >= M) continue;
        float bs = bias[m], sc = scale[m], sh = shift[m];
        #pragma unroll
        for (int jj = 0; jj < 4; ++jj) {
            int n = n0 + tx * 4 + jj;
            float v = fmaxf((acc[ii][jj] + bs) * sc + sh, 0.f);
            Y[(size_t)b * y_batch_stride + (size_t)m * N_PTS + n] = v;
        }
    }
}

// ---------------------------------------------------------------------------
extern "C" void kernel_launch(void* const* d_in, const int* in_sizes, int n_in,
                              void* d_out, int out_size, void* d_ws, size_t ws_size,
                              hipStream_t stream)
{
    const float* xyz   = (const float*)d_in[0];
    const float* h1    = (const float*)d_in[1];
    const float* h2_in = (const float*)d_in[2];
    const float* dg_w1 = (const float*)d_in[3];
    const float* dg_b1 = (const float*)d_in[4];
    const float* dg_s1 = (const float*)d_in[5];
    const float* dg_t1 = (const float*)d_in[6];
    const float* dg_w2 = (const float*)d_in[7];
    const float* dg_b2 = (const float*)d_in[8];
    const float* dg_s2 = (const float*)d_in[9];
    const float* dg_t2 = (const float*)d_in[10];
    const float* dg_w3 = (const float*)d_in[11];
    const float* dg_b3 = (const float*)d_in[12];
    const float* dg_s3 = (const float*)d_in[13];
    const float* dg_t3 = (const float*)d_in[14];
    const float* ed_w1 = (const float*)d_in[15];
    const float* ed_b1 = (const float*)d_in[16];
    const float* ed_w2 = (const float*)d_in[17];
    const float* ed_b2 = (const float*)d_in[18];
    const float* w1 = (const float*)d_in[19];
    const float* b1 = (const float*)d_in[20];
    const float* s1 = (const float*)d_in[21];
    const float* t1 = (const float*)d_in[22];
    const float* w2 = (const float*)d_in[23];
    const float* b2 = (const float*)d_in[24];
    const float* s2 = (const float*)d_in[25];
    const float* t2 = (const float*)d_in[26];
    const float* w3 = (const float*)d_in[27];
    const float* b3 = (const float*)d_in[28];
    const float* s3 = (const float*)d_in[29];
    const float* t3 = (const float*)d_in[30];

    float* out = (float*)d_out;

    // workspace layout (all offsets 256B-aligned)
    char* ws = (char*)d_ws;
    unsigned int* maxd2 = (unsigned int*)ws;
    size_t off = 256;
    float* zin  = (float*)(ws + off); off += (size_t)BATCH * 164 * N_PTS * 4;  // 10.75 MB
    float* bufA = (float*)(ws + off); off += (size_t)BATCH * 256 * N_PTS * 4;  // 16 MB
    float* bufB = (float*)(ws + off); off += (size_t)BATCH * 512 * N_PTS * 4;  // 32 MB
    float* bufC = (float*)(ws + off); off += (size_t)BATCH * 64  * N_PTS * 4;  // 4 MB

    init_maxd2_kernel<<<1, 64, 0, stream>>>(maxd2);

    dim3 gpts(N_PTS / 64, BATCH);
    radius_max_kernel<<<gpts, 256, 0, stream>>>(xyz, maxd2);
    eigen_kernel<<<gpts, 256, 0, stream>>>(xyz, maxd2, ed_w1, ed_b1, ed_w2, ed_b2, zin);

    copy_h1_kernel<<<(BATCH * 128 * N_PTS / 4 + 255) / 256, 256, 0, stream>>>(h1, zin);
    xyz_out_kernel<<<(BATCH * N_PTS * 3 + 255) / 256, 256, 0, stream>>>(xyz, out);

    auto gemm = [&](const float* Wp, const float* Xp, const float* bi,
                    const float* sc, const float* sh, float* Yp,
                    int M, int K, size_t ybs) {
        dim3 grid(N_PTS / 64, (M + 63) / 64, BATCH);
        conv_bn_relu_gemm<<<grid, 256, 0, stream>>>(Wp, Xp, bi, sc, sh, Yp, M, K, ybs);
    };

    // DG stack: 1024 -> 256 -> 64 -> 32 (last writes z_in channels 128..159)
    gemm(dg_w1, h2_in, dg_b1, dg_s1, dg_t1, bufA, 256, 1024, (size_t)256 * N_PTS);
    gemm(dg_w2, bufA,  dg_b2, dg_s2, dg_t2, bufC, 64,  256,  (size_t)64 * N_PTS);
    gemm(dg_w3, bufC,  dg_b3, dg_s3, dg_t3, zin + (size_t)128 * N_PTS, 32, 64, (size_t)164 * N_PTS);

    // Final MLP: 164 -> 512 -> 256 -> 128 (last writes f32 into d_out after xyz)
    gemm(w1, zin,  b1, s1, t1, bufB, 512, 164, (size_t)512 * N_PTS);
    gemm(w2, bufB, b2, s2, t2, bufA, 256, 512, (size_t)256 * N_PTS);
    gemm(w3, bufA, b3, s3, t3, out + BATCH * N_PTS * 3, 128, 256, (size_t)128 * N_PTS);
}

// Round 5
// 309.192 us; speedup vs baseline: 1.4011x; 1.4011x over previous
//
#include <hip/hip_runtime.h>
#include <math.h>

#define N_PTS 4096
#define BATCH 4

typedef short bf16x8 __attribute__((ext_vector_type(8)));
typedef float f32x4 __attribute__((ext_vector_type(4)));
typedef _Float16 f16x8 __attribute__((ext_vector_type(8)));

// f32 -> fp16 (RNE), bit pattern in short
__device__ inline short f2h(float f) {
    _Float16 h = (_Float16)f;
    return __builtin_bit_cast(short, h);
}

// ---------------------------------------------------------------------------
// maxd2 init
// ---------------------------------------------------------------------------
__global__ void init_maxd2_kernel(unsigned int* p) {
    if (threadIdx.x < BATCH) p[threadIdx.x] = 0u;
}

// ---------------------------------------------------------------------------
// Per-batch max pairwise squared distance. Grid: (N/64, B), 256 threads.
// ---------------------------------------------------------------------------
__global__ __launch_bounds__(256) void radius_max_kernel(
    const float* __restrict__ xyz, unsigned int* __restrict__ maxd2)
{
    const int b = blockIdx.y;
    __shared__ float sx[N_PTS], sy[N_PTS], sz[N_PTS];
    const float* xb = xyz + (size_t)b * N_PTS * 3;
    for (int idx = threadIdx.x; idx < N_PTS; idx += 256) {
        sx[idx] = xb[idx * 3 + 0];
        sy[idx] = xb[idx * 3 + 1];
        sz[idx] = xb[idx * 3 + 2];
    }
    __syncthreads();
    const int il = threadIdx.x & 63;
    const int jq = threadIdx.x >> 6;
    const int i = blockIdx.x * 64 + il;
    const float xi = sx[i], yi = sy[i], zi = sz[i];
    float m = 0.f;
    const int j0 = jq * (N_PTS / 4);
    for (int j = j0; j < j0 + N_PTS / 4; ++j) {
        float dx = xi - sx[j], dy = yi - sy[j], dz = zi - sz[j];
        float d2 = dx * dx + dy * dy + dz * dz;
        m = fmaxf(m, d2);
    }
    for (int off = 32; off >= 1; off >>= 1) m = fmaxf(m, __shfl_down(m, off));
    __shared__ float wred[4];
    if ((threadIdx.x & 63) == 0) wred[threadIdx.x >> 6] = m;
    __syncthreads();
    if (threadIdx.x == 0) {
        float mm = fmaxf(fmaxf(wred[0], wred[1]), fmaxf(wred[2], wred[3]));
        atomicMax(&maxd2[b], __float_as_uint(mm));
    }
}

// ---------------------------------------------------------------------------
// Eigen-feature branch -> fp16 zin channels 160..163 (zin has 192 channels)
// ---------------------------------------------------------------------------
__global__ __launch_bounds__(256) void eigen_kernel(
    const float* __restrict__ xyz, const unsigned int* __restrict__ maxd2,
    const float* __restrict__ ew1, const float* __restrict__ eb1,
    const float* __restrict__ ew2, const float* __restrict__ eb2,
    short* __restrict__ zin)
{
    const int b = blockIdx.y;
    __shared__ float sx[N_PTS], sy[N_PTS], sz[N_PTS];
    __shared__ float red[4][64][10];
    const float* xb = xyz + (size_t)b * N_PTS * 3;
    for (int idx = threadIdx.x; idx < N_PTS; idx += 256) {
        sx[idx] = xb[idx * 3 + 0];
        sy[idx] = xb[idx * 3 + 1];
        sz[idx] = xb[idx * 3 + 2];
    }
    __syncthreads();
    const int il = threadIdx.x & 63;
    const int jq = threadIdx.x >> 6;
    const int i = blockIdx.x * 64 + il;
    const float xi = sx[i], yi = sy[i], zi = sz[i];
    const float md2 = __uint_as_float(maxd2[b]);
    const float radius = 0.1f * sqrtf(md2);
    const float r2 = radius * radius;

    float acc[10] = {0.f,0.f,0.f,0.f,0.f,0.f,0.f,0.f,0.f,0.f};
    const int j0 = jq * (N_PTS / 4);
    for (int j = j0; j < j0 + N_PTS / 4; ++j) {
        float xj = sx[j], yj = sy[j], zj = sz[j];
        float dx = xi - xj, dy = yi - yj, dz = zi - zj;
        float d2 = dx * dx + dy * dy + dz * dz;
        if (d2 < r2 && j != i) {
            acc[0] += 1.f;
            acc[1] += xj;      acc[2] += yj;      acc[3] += zj;
            acc[4] += xj * xj; acc[5] += xj * yj; acc[6] += xj * zj;
            acc[7] += yj * yj; acc[8] += yj * zj; acc[9] += zj * zj;
        }
    }
    #pragma unroll
    for (int q = 0; q < 10; ++q) red[jq][il][q] = acc[q];
    __syncthreads();

    if (threadIdx.x < 64) {
        double s[10];
        #pragma unroll
        for (int q = 0; q < 10; ++q)
            s[q] = (double)red[0][il][q] + (double)red[1][il][q] +
                   (double)red[2][il][q] + (double)red[3][il][q];
        double cnt = s[0];
        double denom = fmax(cnt, 1.0);
        double mx = s[1] / denom, my = s[2] / denom, mz = s[3] / denom;
        const double invN = 1.0 / (double)N_PTS;
        double c00 = (s[4] - cnt * mx * mx) * invN;
        double c01 = (s[5] - cnt * mx * my) * invN;
        double c02 = (s[6] - cnt * mx * mz) * invN;
        double c11 = (s[7] - cnt * my * my) * invN;
        double c12 = (s[8] - cnt * my * mz) * invN;
        double c22 = (s[9] - cnt * mz * mz) * invN;

        double qm = (c00 + c11 + c22) / 3.0;
        double p1 = c01*c01 + c02*c02 + c12*c12;
        double a0 = c00 - qm, a1 = c11 - qm, a2 = c22 - qm;
        double p2 = a0*a0 + a1*a1 + a2*a2 + 2.0*p1;
        double e_lo, e_mid, e_hi;
        if (p2 < 1e-32) {
            e_lo = e_mid = e_hi = qm;
        } else {
            double p = sqrt(p2 / 6.0);
            double inv = 1.0 / p;
            double b00 = a0*inv, b11 = a1*inv, b22 = a2*inv;
            double b01 = c01*inv, b02 = c02*inv, b12 = c12*inv;
            double detB = b00*(b11*b22 - b12*b12)
                        - b01*(b01*b22 - b12*b02)
                        + b02*(b01*b12 - b11*b02);
            double r = 0.5 * detB;
            r = fmin(1.0, fmax(-1.0, r));
            double phi = acos(r) / 3.0;
            double two_p = 2.0 * p;
            e_hi = qm + two_p * cos(phi);
            e_lo = qm + two_p * cos(phi + 2.0943951023931953);
            e_mid = 3.0 * qm - e_hi - e_lo;
        }
        float e0 = (float)e_lo, e1 = (float)e_mid, e2 = (float)e_hi;

        float t[4];
        #pragma unroll
        for (int o = 0; o < 4; ++o)
            t[o] = fmaxf(e0 * ew1[o*3+0] + e1 * ew1[o*3+1] +
                         e2 * ew1[o*3+2] + eb1[o], 0.f);
        #pragma unroll
        for (int o = 0; o < 4; ++o) {
            float h = t[0]*ew2[o*4+0] + t[1]*ew2[o*4+1] +
                      t[2]*ew2[o*4+2] + t[3]*ew2[o*4+3] + eb2[o];
            zin[((size_t)b * 192 + 160 + o) * N_PTS + i] = f2h(h);
        }
    }
}

// ---------------------------------------------------------------------------
// h1 f32 -> zin fp16 ch 0..127; zero-fill ch 164..191 (every call)
// ---------------------------------------------------------------------------
__global__ __launch_bounds__(256) void h1_zin_kernel(
    const float* __restrict__ h1, short* __restrict__ zin)
{
    int id = blockIdx.x * 256 + threadIdx.x;
    const int T1 = BATCH * 128 * (N_PTS / 8);
    const int T2 = BATCH * 28 * (N_PTS / 8);
    if (id < T1) {
        size_t e = (size_t)id * 8;
        int n = (int)(e & (N_PTS - 1));
        int c = (int)((e >> 12) & 127);
        int bq = (int)(e >> 19);
        const float* s = h1 + e;
        float4 lo = *(const float4*)s, hi = *(const float4*)(s + 4);
        bf16x8 v;
        v[0]=f2h(lo.x); v[1]=f2h(lo.y); v[2]=f2h(lo.z); v[3]=f2h(lo.w);
        v[4]=f2h(hi.x); v[5]=f2h(hi.y); v[6]=f2h(hi.z); v[7]=f2h(hi.w);
        *(bf16x8*)&zin[((size_t)bq * 192 + c) * N_PTS + n] = v;
    } else if (id < T1 + T2) {
        int id2 = id - T1;
        int n8 = id2 & (N_PTS / 8 - 1);
        int rest = id2 >> 9;
        int c = rest % 28, bq = rest / 28;
        bf16x8 z = {0,0,0,0,0,0,0,0};
        *(bf16x8*)&zin[((size_t)bq * 192 + 164 + c) * N_PTS + n8 * 8] = z;
    }
}

// ---------------------------------------------------------------------------
// xyz passthrough (f32)
// ---------------------------------------------------------------------------
__global__ __launch_bounds__(256) void xyz_out_kernel(
    const float* __restrict__ xyz, float* __restrict__ out)
{
    int idx = blockIdx.x * 256 + threadIdx.x;
    if (idx < BATCH * N_PTS * 3) out[idx] = xyz[idx];
}

// ---------------------------------------------------------------------------
// Weight f32 -> fp16, k-LINEAR (no permutation), zero-padded to [Mp][Kp]
// ---------------------------------------------------------------------------
__global__ __launch_bounds__(256) void conv_weight_kernel(
    const float* __restrict__ W, short* __restrict__ Wb,
    int M, int K, int Mp, int Kp)
{
    int id = blockIdx.x * 256 + threadIdx.x;
    if (id >= Mp * Kp) return;
    int mrow = id / Kp, k = id - mrow * Kp;
    float v = (mrow < M && k < K) ? W[(size_t)mrow * K + k] : 0.f;
    Wb[(size_t)mrow * Kp + k] = f2h(v);
}

// ---------------------------------------------------------------------------
// fp16 MFMA GEMM (simplified, correct-by-construction):
//   Y[b,m,n] = relu((sum_k W[m,k] X[b,k,n] + bias)*scale + shift)
// 256 threads = 4 waves (2x2), wave-tile (BM/2)x(BN/2), 16x16x32 f16 MFMA.
// W tile staged k-linear: Wl[m][0..31]; X tile TRANSPOSED: Xl[n][0..31].
// Both fragments read as *(bf16x8*)&T[row][g*8]  (same bijection
// pi(g,s)=g*8+s on A and B => product correct for any hardware layout).
// Padded stride 40 shorts (80 B, 16B-aligned). Single-buffered, 2 barriers.
// ---------------------------------------------------------------------------
template<int BM, int BN, bool XF32, bool OUTF32>
__global__ __launch_bounds__(256) void mfma_gemm(
    const short* __restrict__ Wb, const void* __restrict__ Xv,
    const float* __restrict__ bias, const float* __restrict__ scale,
    const float* __restrict__ shift, void* __restrict__ Yv,
    int M, int Kp, size_t ybs)
{
    constexpr int LDW = 40;                    // padded LDS stride (shorts)
    constexpr int FM = BM / 32, FN = BN / 32;  // frags per wave (m,n)
    constexpr int WPT = (BM * 4) / 256;        // W 16B-chunks per thread
    constexpr int XPT = (32 * (BN / 8)) / 256; // X 16B-chunks per thread
    __shared__ __align__(16) short Wl[BM][LDW];
    __shared__ __align__(16) short Xl[BN][LDW];

    const int tid = threadIdx.x;
    const int lane = tid & 63, wave = tid >> 6;
    const int g = lane >> 4, r = lane & 15;
    const int wr = wave >> 1, wc = wave & 1;
    const int wm0 = wr * (BM / 2), wn0 = wc * (BN / 2);
    const int b = blockIdx.z;
    const int m0 = blockIdx.y * BM, n0 = blockIdx.x * BN;
    const int NT = Kp >> 5;

    f32x4 acc[FM][FN];
    #pragma unroll
    for (int i = 0; i < FM; ++i)
        #pragma unroll
        for (int jj = 0; jj < FN; ++jj)
            acc[i][jj] = (f32x4){0.f, 0.f, 0.f, 0.f};

    for (int t = 0; t < NT; ++t) {
        // stage W tile (k-linear, vector 16B loads + vector LDS writes)
        #pragma unroll
        for (int u = 0; u < WPT; ++u) {
            int id = u * 256 + tid;
            int m = id >> 2, c4 = id & 3;
            bf16x8 w = *(const bf16x8*)&Wb[(size_t)(m0 + m) * Kp + (t << 5) + c4 * 8];
            *(bf16x8*)&Wl[m][c4 * 8] = w;
        }
        // stage X tile transposed: coalesced 16B global read, scalar LDS scatter
        #pragma unroll
        for (int u = 0; u < XPT; ++u) {
            int id = u * 256 + tid;
            int h = id & (BN / 8 - 1);     // n-chunk (8 cols)
            int k = id / (BN / 8);         // k-row 0..31
            size_t gofs = ((size_t)b * Kp + (t << 5) + k) * N_PTS + n0 + h * 8;
            bf16x8 v;
            if constexpr (XF32) {
                const float* p = (const float*)Xv + gofs;
                float4 lo = *(const float4*)p;
                float4 hi = *(const float4*)(p + 4);
                v[0]=f2h(lo.x); v[1]=f2h(lo.y); v[2]=f2h(lo.z); v[3]=f2h(lo.w);
                v[4]=f2h(hi.x); v[5]=f2h(hi.y); v[6]=f2h(hi.z); v[7]=f2h(hi.w);
            } else {
                v = *(const bf16x8*)((const short*)Xv + gofs);
            }
            #pragma unroll
            for (int j = 0; j < 8; ++j) Xl[h * 8 + j][k] = v[j];
        }
        __syncthreads();

        // compute: A and B fragments via identical ds_read_b128 pattern
        #pragma unroll
        for (int fn = 0; fn < FN; ++fn) {
            bf16x8 bb = *(const bf16x8*)&Xl[wn0 + fn * 16 + r][g * 8];
            #pragma unroll
            for (int fm = 0; fm < FM; ++fm) {
                bf16x8 a = *(const bf16x8*)&Wl[wm0 + fm * 16 + r][g * 8];
                acc[fm][fn] = __builtin_amdgcn_mfma_f32_16x16x32_f16(
                    __builtin_bit_cast(f16x8, a),
                    __builtin_bit_cast(f16x8, bb),
                    acc[fm][fn], 0, 0, 0);
            }
        }
        __syncthreads();
    }

    // epilogue: C/D layout col=lane&15, row=(lane>>4)*4+reg  [m89/m91]
    #pragma unroll
    for (int fm = 0; fm < FM; ++fm) {
        int mbase = m0 + wm0 + fm * 16 + g * 4;
        #pragma unroll
        for (int e = 0; e < 4; ++e) {
            int mm = mbase + e;
            if (mm >= M) continue;
            float bs = bias[mm], sc = scale[mm], sh = shift[mm];
            #pragma unroll
            for (int fn = 0; fn < FN; ++fn) {
                int n = n0 + wn0 + fn * 16 + r;
                float v = fmaxf(fmaf(acc[fm][fn][e] + bs, sc, sh), 0.f);
                size_t o = (size_t)b * ybs + (size_t)mm * N_PTS + n;
                if constexpr (OUTF32) ((float*)Yv)[o] = v;
                else                  ((short*)Yv)[o] = f2h(v);
            }
        }
    }
}

// ---------------------------------------------------------------------------
extern "C" void kernel_launch(void* const* d_in, const int* in_sizes, int n_in,
                              void* d_out, int out_size, void* d_ws, size_t ws_size,
                              hipStream_t stream)
{
    const float* xyz   = (const float*)d_in[0];
    const float* h1    = (const float*)d_in[1];
    const float* h2_in = (const float*)d_in[2];
    const float* dg_w1 = (const float*)d_in[3];
    const float* dg_b1 = (const float*)d_in[4];
    const float* dg_s1 = (const float*)d_in[5];
    const float* dg_t1 = (const float*)d_in[6];
    const float* dg_w2 = (const float*)d_in[7];
    const float* dg_b2 = (const float*)d_in[8];
    const float* dg_s2 = (const float*)d_in[9];
    const float* dg_t2 = (const float*)d_in[10];
    const float* dg_w3 = (const float*)d_in[11];
    const float* dg_b3 = (const float*)d_in[12];
    const float* dg_s3 = (const float*)d_in[13];
    const float* dg_t3 = (const float*)d_in[14];
    const float* ed_w1 = (const float*)d_in[15];
    const float* ed_b1 = (const float*)d_in[16];
    const float* ed_w2 = (const float*)d_in[17];
    const float* ed_b2 = (const float*)d_in[18];
    const float* w1 = (const float*)d_in[19];
    const float* b1 = (const float*)d_in[20];
    const float* s1 = (const float*)d_in[21];
    const float* t1 = (const float*)d_in[22];
    const float* w2 = (const float*)d_in[23];
    const float* b2 = (const float*)d_in[24];
    const float* s2 = (const float*)d_in[25];
    const float* t2 = (const float*)d_in[26];
    const float* w3 = (const float*)d_in[27];
    const float* b3 = (const float*)d_in[28];
    const float* s3 = (const float*)d_in[29];
    const float* t3 = (const float*)d_in[30];

    float* out = (float*)d_out;

    // workspace layout
    char* ws = (char*)d_ws;
    size_t off = 0;
    auto alloc = [&](size_t bytes) {
        char* p = ws + off;
        off += (bytes + 255) & ~(size_t)255;
        return p;
    };
    unsigned int* maxd2 = (unsigned int*)alloc(256);
    short* wb1  = (short*)alloc((size_t)256 * 1024 * 2);
    short* wb2  = (short*)alloc((size_t)64  * 256  * 2);
    short* wb3  = (short*)alloc((size_t)64  * 64   * 2);
    short* wbf1 = (short*)alloc((size_t)512 * 192  * 2);
    short* wbf2 = (short*)alloc((size_t)256 * 512  * 2);
    short* wbf3 = (short*)alloc((size_t)128 * 256  * 2);
    short* zin  = (short*)alloc((size_t)BATCH * 192 * N_PTS * 2);
    short* bufA = (short*)alloc((size_t)BATCH * 256 * N_PTS * 2);
    short* bufC = (short*)alloc((size_t)BATCH * 64  * N_PTS * 2);
    short* bufB = (short*)alloc((size_t)BATCH * 512 * N_PTS * 2);
    short* bufD = (short*)alloc((size_t)BATCH * 256 * N_PTS * 2);

    init_maxd2_kernel<<<1, 64, 0, stream>>>(maxd2);

    // weight conversions (k-linear fp16, zero-padded)
    auto wconv = [&](const float* W, short* Wb, int M, int K, int Mp, int Kp) {
        conv_weight_kernel<<<(Mp * Kp + 255) / 256, 256, 0, stream>>>(W, Wb, M, K, Mp, Kp);
    };
    wconv(dg_w1, wb1, 256, 1024, 256, 1024);
    wconv(dg_w2, wb2, 64, 256, 64, 256);
    wconv(dg_w3, wb3, 32, 64, 64, 64);
    wconv(w1, wbf1, 512, 164, 512, 192);
    wconv(w2, wbf2, 256, 512, 256, 512);
    wconv(w3, wbf3, 128, 256, 128, 256);

    dim3 gpts(N_PTS / 64, BATCH);
    radius_max_kernel<<<gpts, 256, 0, stream>>>(xyz, maxd2);
    eigen_kernel<<<gpts, 256, 0, stream>>>(xyz, maxd2, ed_w1, ed_b1, ed_w2, ed_b2, zin);

    {
        int total = BATCH * 128 * (N_PTS / 8) + BATCH * 28 * (N_PTS / 8);
        h1_zin_kernel<<<(total + 255) / 256, 256, 0, stream>>>(h1, zin);
    }
    xyz_out_kernel<<<(BATCH * N_PTS * 3 + 255) / 256, 256, 0, stream>>>(xyz, out);

    // GEMM chain
    // DG1: 1024 -> 256  (X = h2_in f32)
    mfma_gemm<128, 128, true, false><<<dim3(N_PTS/128, 2, BATCH), 256, 0, stream>>>(
        wb1, h2_in, dg_b1, dg_s1, dg_t1, bufA, 256, 1024, (size_t)256 * N_PTS);
    // DG2: 256 -> 64
    mfma_gemm<64, 64, false, false><<<dim3(N_PTS/64, 1, BATCH), 256, 0, stream>>>(
        wb2, bufA, dg_b2, dg_s2, dg_t2, bufC, 64, 256, (size_t)64 * N_PTS);
    // DG3: 64 -> 32 (into zin ch 128..159)
    mfma_gemm<64, 64, false, false><<<dim3(N_PTS/64, 1, BATCH), 256, 0, stream>>>(
        wb3, bufC, dg_b3, dg_s3, dg_t3, zin + (size_t)128 * N_PTS, 32, 64, (size_t)192 * N_PTS);
    // F1: 192 -> 512
    mfma_gemm<128, 128, false, false><<<dim3(N_PTS/128, 4, BATCH), 256, 0, stream>>>(
        wbf1, zin, b1, s1, t1, bufB, 512, 192, (size_t)512 * N_PTS);
    // F2: 512 -> 256
    mfma_gemm<128, 128, false, false><<<dim3(N_PTS/128, 2, BATCH), 256, 0, stream>>>(
        wbf2, bufB, b2, s2, t2, bufD, 256, 512, (size_t)256 * N_PTS);
    // F3: 256 -> 128 (f32 into d_out after xyz)
    mfma_gemm<128, 64, false, true><<<dim3(N_PTS/64, 1, BATCH), 256, 0, stream>>>(
        wbf3, bufD, b3, s3, t3, out + (size_t)BATCH * N_PTS * 3, 128, 256, (size_t)128 * N_PTS);
}

// Round 6
// 238.027 us; speedup vs baseline: 1.8200x; 1.2990x over previous
//
#include <hip/hip_runtime.h>
#include <math.h>

#define N_PTS 4096
#define BATCH 4
#define JS 8                  // j-split factor
#define JCH (N_PTS / JS)      // 512 points per j-chunk

typedef short bf16x8 __attribute__((ext_vector_type(8)));
typedef float f32x4 __attribute__((ext_vector_type(4)));
typedef _Float16 f16x8 __attribute__((ext_vector_type(8)));

// f32 -> fp16 (RNE), bit pattern in short
__device__ inline short f2h(float f) {
    _Float16 h = (_Float16)f;
    return __builtin_bit_cast(short, h);
}

// ---------------------------------------------------------------------------
// maxd2 init
// ---------------------------------------------------------------------------
__global__ void init_maxd2_kernel(unsigned int* p) {
    if (threadIdx.x < BATCH) p[threadIdx.x] = 0u;
}

// ---------------------------------------------------------------------------
// Per-batch max pairwise squared distance.
// Grid: (N/64, JS, B), 256 threads. Block stages a 512-pt j-chunk (float4).
// 64 i-lanes x 4 wave j-subranges of 128. atomicMax(uint) is order-invariant.
// ---------------------------------------------------------------------------
__global__ __launch_bounds__(256) void radius_max_kernel(
    const float* __restrict__ xyz, unsigned int* __restrict__ maxd2)
{
    const int b = blockIdx.z;
    __shared__ float4 sj[JCH];
    const float* xb = xyz + (size_t)b * N_PTS * 3;
    const int j0 = blockIdx.y * JCH;
    for (int idx = threadIdx.x; idx < JCH; idx += 256) {
        int j = j0 + idx;
        sj[idx] = make_float4(xb[j*3+0], xb[j*3+1], xb[j*3+2], 0.f);
    }
    __syncthreads();
    const int il = threadIdx.x & 63;
    const int jq = threadIdx.x >> 6;
    const int i = blockIdx.x * 64 + il;
    const float xi = xb[i*3+0], yi = xb[i*3+1], zi = xb[i*3+2];
    float m = 0.f;
    const int jb = jq * (JCH / 4);
    #pragma unroll 4
    for (int j = jb; j < jb + JCH / 4; ++j) {
        float4 p = sj[j];
        float dx = xi - p.x, dy = yi - p.y, dz = zi - p.z;
        m = fmaxf(m, dx * dx + dy * dy + dz * dz);
    }
    for (int off = 32; off >= 1; off >>= 1) m = fmaxf(m, __shfl_down(m, off));
    __shared__ float wred[4];
    if ((threadIdx.x & 63) == 0) wred[threadIdx.x >> 6] = m;
    __syncthreads();
    if (threadIdx.x == 0) {
        float mm = fmaxf(fmaxf(wred[0], wred[1]), fmaxf(wred[2], wred[3]));
        atomicMax(&maxd2[b], __float_as_uint(mm));
    }
}

// ---------------------------------------------------------------------------
// Eigen accumulate: per-(i, j-chunk) partial (cnt,S1,S2). Self INCLUDED
// (subtracted in finalize) so the hot loop is just d2<r2 + masked adds.
// Grid: (N/64, JS, B), 256 threads. pbuf[b][js][i][10] written once each.
// ---------------------------------------------------------------------------
__global__ __launch_bounds__(256) void eigen_accum_kernel(
    const float* __restrict__ xyz, const unsigned int* __restrict__ maxd2,
    float* __restrict__ pbuf)
{
    const int b = blockIdx.z, js = blockIdx.y;
    __shared__ float4 sj[JCH];
    __shared__ float red[4][64][10];
    const float* xb = xyz + (size_t)b * N_PTS * 3;
    const int j0 = js * JCH;
    for (int idx = threadIdx.x; idx < JCH; idx += 256) {
        int j = j0 + idx;
        sj[idx] = make_float4(xb[j*3+0], xb[j*3+1], xb[j*3+2], 0.f);
    }
    __syncthreads();
    const int il = threadIdx.x & 63;
    const int jq = threadIdx.x >> 6;
    const int i = blockIdx.x * 64 + il;
    const float xi = xb[i*3+0], yi = xb[i*3+1], zi = xb[i*3+2];
    const float r2 = 0.01f * __uint_as_float(maxd2[b]);   // (0.1*maxd)^2

    float acc[10] = {0.f,0.f,0.f,0.f,0.f,0.f,0.f,0.f,0.f,0.f};
    const int jb = jq * (JCH / 4);
    for (int j = jb; j < jb + JCH / 4; ++j) {
        float4 p = sj[j];
        float dx = xi - p.x, dy = yi - p.y, dz = zi - p.z;
        float d2 = dx * dx + dy * dy + dz * dz;
        if (d2 < r2) {                      // self included; removed later
            acc[0] += 1.f;
            acc[1] += p.x;       acc[2] += p.y;       acc[3] += p.z;
            acc[4] += p.x * p.x; acc[5] += p.x * p.y; acc[6] += p.x * p.z;
            acc[7] += p.y * p.y; acc[8] += p.y * p.z; acc[9] += p.z * p.z;
        }
    }
    #pragma unroll
    for (int q = 0; q < 10; ++q) red[jq][il][q] = acc[q];
    __syncthreads();
    if (threadIdx.x < 64) {
        float* dst = pbuf + ((size_t)(b * JS + js) * N_PTS + i) * 10;
        #pragma unroll
        for (int q = 0; q < 10; ++q)
            dst[q] = red[0][il][q] + red[1][il][q] + red[2][il][q] + red[3][il][q];
    }
}

// ---------------------------------------------------------------------------
// Eigen finalize: sum JS partials (double), subtract self, Cardano eigvalsh,
// fused 3->4->4 ED MLP -> fp16 zin channels 160..163. One thread per point.
// ---------------------------------------------------------------------------
__global__ __launch_bounds__(256) void eigen_finalize_kernel(
    const float* __restrict__ xyz, const float* __restrict__ pbuf,
    const float* __restrict__ ew1, const float* __restrict__ eb1,
    const float* __restrict__ ew2, const float* __restrict__ eb2,
    short* __restrict__ zin)
{
    int id = blockIdx.x * 256 + threadIdx.x;
    if (id >= BATCH * N_PTS) return;
    int b = id >> 12, i = id & (N_PTS - 1);

    double s[10] = {0,0,0,0,0,0,0,0,0,0};
    for (int js = 0; js < JS; ++js) {
        const float* src = pbuf + ((size_t)(b * JS + js) * N_PTS + i) * 10;
        #pragma unroll
        for (int q = 0; q < 10; ++q) s[q] += (double)src[q];
    }
    // subtract self contribution (added as f32 products in accum)
    const float* xb = xyz + (size_t)b * N_PTS * 3;
    float xi = xb[i*3+0], yi = xb[i*3+1], zi = xb[i*3+2];
    s[0] -= 1.0;
    s[1] -= (double)xi;        s[2] -= (double)yi;        s[3] -= (double)zi;
    s[4] -= (double)(xi * xi); s[5] -= (double)(xi * yi); s[6] -= (double)(xi * zi);
    s[7] -= (double)(yi * yi); s[8] -= (double)(yi * zi); s[9] -= (double)(zi * zi);

    double cnt = s[0];
    double denom = fmax(cnt, 1.0);
    double mx = s[1] / denom, my = s[2] / denom, mz = s[3] / denom;
    const double invN = 1.0 / (double)N_PTS;
    double c00 = (s[4] - cnt * mx * mx) * invN;
    double c01 = (s[5] - cnt * mx * my) * invN;
    double c02 = (s[6] - cnt * mx * mz) * invN;
    double c11 = (s[7] - cnt * my * my) * invN;
    double c12 = (s[8] - cnt * my * mz) * invN;
    double c22 = (s[9] - cnt * mz * mz) * invN;

    double qm = (c00 + c11 + c22) / 3.0;
    double p1 = c01*c01 + c02*c02 + c12*c12;
    double a0 = c00 - qm, a1 = c11 - qm, a2 = c22 - qm;
    double p2 = a0*a0 + a1*a1 + a2*a2 + 2.0*p1;
    double e_lo, e_mid, e_hi;
    if (p2 < 1e-32) {
        e_lo = e_mid = e_hi = qm;
    } else {
        double p = sqrt(p2 / 6.0);
        double inv = 1.0 / p;
        double b00 = a0*inv, b11 = a1*inv, b22 = a2*inv;
        double b01 = c01*inv, b02 = c02*inv, b12 = c12*inv;
        double detB = b00*(b11*b22 - b12*b12)
                    - b01*(b01*b22 - b12*b02)
                    + b02*(b01*b12 - b11*b02);
        double r = 0.5 * detB;
        r = fmin(1.0, fmax(-1.0, r));
        double phi = acos(r) / 3.0;
        double two_p = 2.0 * p;
        e_hi = qm + two_p * cos(phi);
        e_lo = qm + two_p * cos(phi + 2.0943951023931953);
        e_mid = 3.0 * qm - e_hi - e_lo;
    }
    float e0 = (float)e_lo, e1 = (float)e_mid, e2 = (float)e_hi;

    float t[4];
    #pragma unroll
    for (int o = 0; o < 4; ++o)
        t[o] = fmaxf(e0 * ew1[o*3+0] + e1 * ew1[o*3+1] +
                     e2 * ew1[o*3+2] + eb1[o], 0.f);
    #pragma unroll
    for (int o = 0; o < 4; ++o) {
        float h = t[0]*ew2[o*4+0] + t[1]*ew2[o*4+1] +
                  t[2]*ew2[o*4+2] + t[3]*ew2[o*4+3] + eb2[o];
        zin[((size_t)b * 192 + 160 + o) * N_PTS + i] = f2h(h);
    }
}

// ---------------------------------------------------------------------------
// h1 f32 -> zin fp16 ch 0..127; zero-fill ch 164..191 (every call)
// ---------------------------------------------------------------------------
__global__ __launch_bounds__(256) void h1_zin_kernel(
    const float* __restrict__ h1, short* __restrict__ zin)
{
    int id = blockIdx.x * 256 + threadIdx.x;
    const int T1 = BATCH * 128 * (N_PTS / 8);
    const int T2 = BATCH * 28 * (N_PTS / 8);
    if (id < T1) {
        size_t e = (size_t)id * 8;
        int n = (int)(e & (N_PTS - 1));
        int c = (int)((e >> 12) & 127);
        int bq = (int)(e >> 19);
        const float* s = h1 + e;
        float4 lo = *(const float4*)s, hi = *(const float4*)(s + 4);
        bf16x8 v;
        v[0]=f2h(lo.x); v[1]=f2h(lo.y); v[2]=f2h(lo.z); v[3]=f2h(lo.w);
        v[4]=f2h(hi.x); v[5]=f2h(hi.y); v[6]=f2h(hi.z); v[7]=f2h(hi.w);
        *(bf16x8*)&zin[((size_t)bq * 192 + c) * N_PTS + n] = v;
    } else if (id < T1 + T2) {
        int id2 = id - T1;
        int n8 = id2 & (N_PTS / 8 - 1);
        int rest = id2 >> 9;
        int c = rest % 28, bq = rest / 28;
        bf16x8 z = {0,0,0,0,0,0,0,0};
        *(bf16x8*)&zin[((size_t)bq * 192 + 164 + c) * N_PTS + n8 * 8] = z;
    }
}

// ---------------------------------------------------------------------------
// xyz passthrough (f32)
// ---------------------------------------------------------------------------
__global__ __launch_bounds__(256) void xyz_out_kernel(
    const float* __restrict__ xyz, float* __restrict__ out)
{
    int idx = blockIdx.x * 256 + threadIdx.x;
    if (idx < BATCH * N_PTS * 3) out[idx] = xyz[idx];
}

// ---------------------------------------------------------------------------
// Weight f32 -> fp16, k-LINEAR (no permutation), zero-padded to [Mp][Kp]
// ---------------------------------------------------------------------------
__global__ __launch_bounds__(256) void conv_weight_kernel(
    const float* __restrict__ W, short* __restrict__ Wb,
    int M, int K, int Mp, int Kp)
{
    int id = blockIdx.x * 256 + threadIdx.x;
    if (id >= Mp * Kp) return;
    int mrow = id / Kp, k = id - mrow * Kp;
    float v = (mrow < M && k < K) ? W[(size_t)mrow * K + k] : 0.f;
    Wb[(size_t)mrow * Kp + k] = f2h(v);
}

// ---------------------------------------------------------------------------
// fp16 MFMA GEMM (simplified, correct-by-construction):
//   Y[b,m,n] = relu((sum_k W[m,k] X[b,k,n] + bias)*scale + shift)
// 256 threads = 4 waves (2x2), wave-tile (BM/2)x(BN/2), 16x16x32 f16 MFMA.
// W tile staged k-linear: Wl[m][0..31]; X tile TRANSPOSED: Xl[n][0..31].
// Both fragments read as *(bf16x8*)&T[row][g*8]  (same bijection
// pi(g,s)=g*8+s on A and B => product correct for any hardware layout).
// Padded stride 40 shorts (80 B, 16B-aligned). Single-buffered, 2 barriers.
// ---------------------------------------------------------------------------
template<int BM, int BN, bool XF32, bool OUTF32>
__global__ __launch_bounds__(256) void mfma_gemm(
    const short* __restrict__ Wb, const void* __restrict__ Xv,
    const float* __restrict__ bias, const float* __restrict__ scale,
    const float* __restrict__ shift, void* __restrict__ Yv,
    int M, int Kp, size_t ybs)
{
    constexpr int LDW = 40;                    // padded LDS stride (shorts)
    constexpr int FM = BM / 32, FN = BN / 32;  // frags per wave (m,n)
    constexpr int WPT = (BM * 4) / 256;        // W 16B-chunks per thread
    constexpr int XPT = (32 * (BN / 8)) / 256; // X 16B-chunks per thread
    __shared__ __align__(16) short Wl[BM][LDW];
    __shared__ __align__(16) short Xl[BN][LDW];

    const int tid = threadIdx.x;
    const int lane = tid & 63, wave = tid >> 6;
    const int g = lane >> 4, r = lane & 15;
    const int wr = wave >> 1, wc = wave & 1;
    const int wm0 = wr * (BM / 2), wn0 = wc * (BN / 2);
    const int b = blockIdx.z;
    const int m0 = blockIdx.y * BM, n0 = blockIdx.x * BN;
    const int NT = Kp >> 5;

    f32x4 acc[FM][FN];
    #pragma unroll
    for (int i = 0; i < FM; ++i)
        #pragma unroll
        for (int jj = 0; jj < FN; ++jj)
            acc[i][jj] = (f32x4){0.f, 0.f, 0.f, 0.f};

    for (int t = 0; t < NT; ++t) {
        // stage W tile (k-linear, vector 16B loads + vector LDS writes)
        #pragma unroll
        for (int u = 0; u < WPT; ++u) {
            int id = u * 256 + tid;
            int m = id >> 2, c4 = id & 3;
            bf16x8 w = *(const bf16x8*)&Wb[(size_t)(m0 + m) * Kp + (t << 5) + c4 * 8];
            *(bf16x8*)&Wl[m][c4 * 8] = w;
        }
        // stage X tile transposed: coalesced 16B global read, scalar LDS scatter
        #pragma unroll
        for (int u = 0; u < XPT; ++u) {
            int id = u * 256 + tid;
            int h = id & (BN / 8 - 1);     // n-chunk (8 cols)
            int k = id / (BN / 8);         // k-row 0..31
            size_t gofs = ((size_t)b * Kp + (t << 5) + k) * N_PTS + n0 + h * 8;
            bf16x8 v;
            if constexpr (XF32) {
                const float* p = (const float*)Xv + gofs;
                float4 lo = *(const float4*)p;
                float4 hi = *(const float4*)(p + 4);
                v[0]=f2h(lo.x); v[1]=f2h(lo.y); v[2]=f2h(lo.z); v[3]=f2h(lo.w);
                v[4]=f2h(hi.x); v[5]=f2h(hi.y); v[6]=f2h(hi.z); v[7]=f2h(hi.w);
            } else {
                v = *(const bf16x8*)((const short*)Xv + gofs);
            }
            #pragma unroll
            for (int j = 0; j < 8; ++j) Xl[h * 8 + j][k] = v[j];
        }
        __syncthreads();

        // compute: A and B fragments via identical ds_read_b128 pattern
        #pragma unroll
        for (int fn = 0; fn < FN; ++fn) {
            bf16x8 bb = *(const bf16x8*)&Xl[wn0 + fn * 16 + r][g * 8];
            #pragma unroll
            for (int fm = 0; fm < FM; ++fm) {
                bf16x8 a = *(const bf16x8*)&Wl[wm0 + fm * 16 + r][g * 8];
                acc[fm][fn] = __builtin_amdgcn_mfma_f32_16x16x32_f16(
                    __builtin_bit_cast(f16x8, a),
                    __builtin_bit_cast(f16x8, bb),
                    acc[fm][fn], 0, 0, 0);
            }
        }
        __syncthreads();
    }

    // epilogue: C/D layout col=lane&15, row=(lane>>4)*4+reg  [m89/m91]
    #pragma unroll
    for (int fm = 0; fm < FM; ++fm) {
        int mbase = m0 + wm0 + fm * 16 + g * 4;
        #pragma unroll
        for (int e = 0; e < 4; ++e) {
            int mm = mbase + e;
            if (mm >= M) continue;
            float bs = bias[mm], sc = scale[mm], sh = shift[mm];
            #pragma unroll
            for (int fn = 0; fn < FN; ++fn) {
                int n = n0 + wn0 + fn * 16 + r;
                float v = fmaxf(fmaf(acc[fm][fn][e] + bs, sc, sh), 0.f);
                size_t o = (size_t)b * ybs + (size_t)mm * N_PTS + n;
                if constexpr (OUTF32) ((float*)Yv)[o] = v;
                else                  ((short*)Yv)[o] = f2h(v);
            }
        }
    }
}

// ---------------------------------------------------------------------------
extern "C" void kernel_launch(void* const* d_in, const int* in_sizes, int n_in,
                              void* d_out, int out_size, void* d_ws, size_t ws_size,
                              hipStream_t stream)
{
    const float* xyz   = (const float*)d_in[0];
    const float* h1    = (const float*)d_in[1];
    const float* h2_in = (const float*)d_in[2];
    const float* dg_w1 = (const float*)d_in[3];
    const float* dg_b1 = (const float*)d_in[4];
    const float* dg_s1 = (const float*)d_in[5];
    const float* dg_t1 = (const float*)d_in[6];
    const float* dg_w2 = (const float*)d_in[7];
    const float* dg_b2 = (const float*)d_in[8];
    const float* dg_s2 = (const float*)d_in[9];
    const float* dg_t2 = (const float*)d_in[10];
    const float* dg_w3 = (const float*)d_in[11];
    const float* dg_b3 = (const float*)d_in[12];
    const float* dg_s3 = (const float*)d_in[13];
    const float* dg_t3 = (const float*)d_in[14];
    const float* ed_w1 = (const float*)d_in[15];
    const float* ed_b1 = (const float*)d_in[16];
    const float* ed_w2 = (const float*)d_in[17];
    const float* ed_b2 = (const float*)d_in[18];
    const float* w1 = (const float*)d_in[19];
    const float* b1 = (const float*)d_in[20];
    const float* s1 = (const float*)d_in[21];
    const float* t1 = (const float*)d_in[22];
    const float* w2 = (const float*)d_in[23];
    const float* b2 = (const float*)d_in[24];
    const float* s2 = (const float*)d_in[25];
    const float* t2 = (const float*)d_in[26];
    const float* w3 = (const float*)d_in[27];
    const float* b3 = (const float*)d_in[28];
    const float* s3 = (const float*)d_in[29];
    const float* t3 = (const float*)d_in[30];

    float* out = (float*)d_out;

    // workspace layout
    char* ws = (char*)d_ws;
    size_t off = 0;
    auto alloc = [&](size_t bytes) {
        char* p = ws + off;
        off += (bytes + 255) & ~(size_t)255;
        return p;
    };
    unsigned int* maxd2 = (unsigned int*)alloc(256);
    short* wb1  = (short*)alloc((size_t)256 * 1024 * 2);
    short* wb2  = (short*)alloc((size_t)64  * 256  * 2);
    short* wb3  = (short*)alloc((size_t)64  * 64   * 2);
    short* wbf1 = (short*)alloc((size_t)512 * 192  * 2);
    short* wbf2 = (short*)alloc((size_t)256 * 512  * 2);
    short* wbf3 = (short*)alloc((size_t)128 * 256  * 2);
    short* zin  = (short*)alloc((size_t)BATCH * 192 * N_PTS * 2);
    short* bufA = (short*)alloc((size_t)BATCH * 256 * N_PTS * 2);
    short* bufC = (short*)alloc((size_t)BATCH * 64  * N_PTS * 2);
    short* bufB = (short*)alloc((size_t)BATCH * 512 * N_PTS * 2);
    short* bufD = (short*)alloc((size_t)BATCH * 256 * N_PTS * 2);
    float* pbuf = (float*)alloc((size_t)BATCH * JS * N_PTS * 10 * 4);  // 5.2 MB

    init_maxd2_kernel<<<1, 64, 0, stream>>>(maxd2);

    // weight conversions (k-linear fp16, zero-padded)
    auto wconv = [&](const float* W, short* Wb, int M, int K, int Mp, int Kp) {
        conv_weight_kernel<<<(Mp * Kp + 255) / 256, 256, 0, stream>>>(W, Wb, M, K, Mp, Kp);
    };
    wconv(dg_w1, wb1, 256, 1024, 256, 1024);
    wconv(dg_w2, wb2, 64, 256, 64, 256);
    wconv(dg_w3, wb3, 32, 64, 64, 64);
    wconv(w1, wbf1, 512, 164, 512, 192);
    wconv(w2, wbf2, 256, 512, 256, 512);
    wconv(w3, wbf3, 128, 256, 128, 256);

    // eigen branch, j-split for occupancy
    dim3 gsplit(N_PTS / 64, JS, BATCH);
    radius_max_kernel<<<gsplit, 256, 0, stream>>>(xyz, maxd2);
    eigen_accum_kernel<<<gsplit, 256, 0, stream>>>(xyz, maxd2, pbuf);
    eigen_finalize_kernel<<<(BATCH * N_PTS + 255) / 256, 256, 0, stream>>>(
        xyz, pbuf, ed_w1, ed_b1, ed_w2, ed_b2, zin);

    {
        int total = BATCH * 128 * (N_PTS / 8) + BATCH * 28 * (N_PTS / 8);
        h1_zin_kernel<<<(total + 255) / 256, 256, 0, stream>>>(h1, zin);
    }
    xyz_out_kernel<<<(BATCH * N_PTS * 3 + 255) / 256, 256, 0, stream>>>(xyz, out);

    // GEMM chain
    // DG1: 1024 -> 256  (X = h2_in f32)
    mfma_gemm<128, 128, true, false><<<dim3(N_PTS/128, 2, BATCH), 256, 0, stream>>>(
        wb1, h2_in, dg_b1, dg_s1, dg_t1, bufA, 256, 1024, (size_t)256 * N_PTS);
    // DG2: 256 -> 64
    mfma_gemm<64, 64, false, false><<<dim3(N_PTS/64, 1, BATCH), 256, 0, stream>>>(
        wb2, bufA, dg_b2, dg_s2, dg_t2, bufC, 64, 256, (size_t)64 * N_PTS);
    // DG3: 64 -> 32 (into zin ch 128..159)
    mfma_gemm<64, 64, false, false><<<dim3(N_PTS/64, 1, BATCH), 256, 0, stream>>>(
        wb3, bufC, dg_b3, dg_s3, dg_t3, zin + (size_t)128 * N_PTS, 32, 64, (size_t)192 * N_PTS);
    // F1: 192 -> 512
    mfma_gemm<128, 128, false, false><<<dim3(N_PTS/128, 4, BATCH), 256, 0, stream>>>(
        wbf1, zin, b1, s1, t1, bufB, 512, 192, (size_t)512 * N_PTS);
    // F2: 512 -> 256
    mfma_gemm<128, 128, false, false><<<dim3(N_PTS/128, 2, BATCH), 256, 0, stream>>>(
        wbf2, bufB, b2, s2, t2, bufD, 256, 512, (size_t)256 * N_PTS);
    // F3: 256 -> 128 (f32 into d_out after xyz)
    mfma_gemm<128, 64, false, true><<<dim3(N_PTS/64, 1, BATCH), 256, 0, stream>>>(
        wbf3, bufD, b3, s3, t3, out + (size_t)BATCH * N_PTS * 3, 128, 256, (size_t)128 * N_PTS);
}

// Round 7
// 186.976 us; speedup vs baseline: 2.3169x; 1.2730x over previous
//
#include <hip/hip_runtime.h>
#include <math.h>

#define N_PTS 4096
#define BATCH 4
#define JS 8                  // j-split factor
#define JCH (N_PTS / JS)      // 512 points per j-chunk

typedef short bf16x8 __attribute__((ext_vector_type(8)));
typedef short bf16x4 __attribute__((ext_vector_type(4)));
typedef float f32x4 __attribute__((ext_vector_type(4)));
typedef _Float16 f16x8 __attribute__((ext_vector_type(8)));

// f32 -> fp16 (RNE), bit pattern in short
__device__ inline short f2h(float f) {
    _Float16 h = (_Float16)f;
    return __builtin_bit_cast(short, h);
}

// ---------------------------------------------------------------------------
// maxd2 init
// ---------------------------------------------------------------------------
__global__ void init_maxd2_kernel(unsigned int* p) {
    if (threadIdx.x < BATCH) p[threadIdx.x] = 0u;
}

// ---------------------------------------------------------------------------
// Per-batch max pairwise squared distance. Grid: (N/64, JS, B), 256 threads.
// ---------------------------------------------------------------------------
__global__ __launch_bounds__(256) void radius_max_kernel(
    const float* __restrict__ xyz, unsigned int* __restrict__ maxd2)
{
    const int b = blockIdx.z;
    __shared__ float4 sj[JCH];
    const float* xb = xyz + (size_t)b * N_PTS * 3;
    const int j0 = blockIdx.y * JCH;
    for (int idx = threadIdx.x; idx < JCH; idx += 256) {
        int j = j0 + idx;
        sj[idx] = make_float4(xb[j*3+0], xb[j*3+1], xb[j*3+2], 0.f);
    }
    __syncthreads();
    const int il = threadIdx.x & 63;
    const int jq = threadIdx.x >> 6;
    const int i = blockIdx.x * 64 + il;
    const float xi = xb[i*3+0], yi = xb[i*3+1], zi = xb[i*3+2];
    float m = 0.f;
    const int jb = jq * (JCH / 4);
    #pragma unroll 4
    for (int j = jb; j < jb + JCH / 4; ++j) {
        float4 p = sj[j];
        float dx = xi - p.x, dy = yi - p.y, dz = zi - p.z;
        m = fmaxf(m, dx * dx + dy * dy + dz * dz);
    }
    for (int off = 32; off >= 1; off >>= 1) m = fmaxf(m, __shfl_down(m, off));
    __shared__ float wred[4];
    if ((threadIdx.x & 63) == 0) wred[threadIdx.x >> 6] = m;
    __syncthreads();
    if (threadIdx.x == 0) {
        float mm = fmaxf(fmaxf(wred[0], wred[1]), fmaxf(wred[2], wred[3]));
        atomicMax(&maxd2[b], __float_as_uint(mm));
    }
}

// ---------------------------------------------------------------------------
// Eigen accumulate: per-(i, j-chunk) partial (cnt,S1,S2). Self INCLUDED.
// Grid: (N/64, JS, B), 256 threads.
// ---------------------------------------------------------------------------
__global__ __launch_bounds__(256) void eigen_accum_kernel(
    const float* __restrict__ xyz, const unsigned int* __restrict__ maxd2,
    float* __restrict__ pbuf)
{
    const int b = blockIdx.z, js = blockIdx.y;
    __shared__ float4 sj[JCH];
    __shared__ float red[4][64][10];
    const float* xb = xyz + (size_t)b * N_PTS * 3;
    const int j0 = js * JCH;
    for (int idx = threadIdx.x; idx < JCH; idx += 256) {
        int j = j0 + idx;
        sj[idx] = make_float4(xb[j*3+0], xb[j*3+1], xb[j*3+2], 0.f);
    }
    __syncthreads();
    const int il = threadIdx.x & 63;
    const int jq = threadIdx.x >> 6;
    const int i = blockIdx.x * 64 + il;
    const float xi = xb[i*3+0], yi = xb[i*3+1], zi = xb[i*3+2];
    const float r2 = 0.01f * __uint_as_float(maxd2[b]);   // (0.1*maxd)^2

    float acc[10] = {0.f,0.f,0.f,0.f,0.f,0.f,0.f,0.f,0.f,0.f};
    const int jb = jq * (JCH / 4);
    for (int j = jb; j < jb + JCH / 4; ++j) {
        float4 p = sj[j];
        float dx = xi - p.x, dy = yi - p.y, dz = zi - p.z;
        float d2 = dx * dx + dy * dy + dz * dz;
        if (d2 < r2) {                      // self included; removed later
            acc[0] += 1.f;
            acc[1] += p.x;       acc[2] += p.y;       acc[3] += p.z;
            acc[4] += p.x * p.x; acc[5] += p.x * p.y; acc[6] += p.x * p.z;
            acc[7] += p.y * p.y; acc[8] += p.y * p.z; acc[9] += p.z * p.z;
        }
    }
    #pragma unroll
    for (int q = 0; q < 10; ++q) red[jq][il][q] = acc[q];
    __syncthreads();
    if (threadIdx.x < 64) {
        float* dst = pbuf + ((size_t)(b * JS + js) * N_PTS + i) * 10;
        #pragma unroll
        for (int q = 0; q < 10; ++q)
            dst[q] = red[0][il][q] + red[1][il][q] + red[2][il][q] + red[3][il][q];
    }
}

// ---------------------------------------------------------------------------
// Eigen finalize -> fp16 zinT[b][n][160..163]  (zinT: [B][N][192])
// ---------------------------------------------------------------------------
__global__ __launch_bounds__(256) void eigen_finalize_kernel(
    const float* __restrict__ xyz, const float* __restrict__ pbuf,
    const float* __restrict__ ew1, const float* __restrict__ eb1,
    const float* __restrict__ ew2, const float* __restrict__ eb2,
    short* __restrict__ zinT)
{
    int id = blockIdx.x * 256 + threadIdx.x;
    if (id >= BATCH * N_PTS) return;
    int b = id >> 12, i = id & (N_PTS - 1);

    double s[10] = {0,0,0,0,0,0,0,0,0,0};
    for (int js = 0; js < JS; ++js) {
        const float* src = pbuf + ((size_t)(b * JS + js) * N_PTS + i) * 10;
        #pragma unroll
        for (int q = 0; q < 10; ++q) s[q] += (double)src[q];
    }
    const float* xb = xyz + (size_t)b * N_PTS * 3;
    float xi = xb[i*3+0], yi = xb[i*3+1], zi = xb[i*3+2];
    s[0] -= 1.0;
    s[1] -= (double)xi;        s[2] -= (double)yi;        s[3] -= (double)zi;
    s[4] -= (double)(xi * xi); s[5] -= (double)(xi * yi); s[6] -= (double)(xi * zi);
    s[7] -= (double)(yi * yi); s[8] -= (double)(yi * zi); s[9] -= (double)(zi * zi);

    double cnt = s[0];
    double denom = fmax(cnt, 1.0);
    double mx = s[1] / denom, my = s[2] / denom, mz = s[3] / denom;
    const double invN = 1.0 / (double)N_PTS;
    double c00 = (s[4] - cnt * mx * mx) * invN;
    double c01 = (s[5] - cnt * mx * my) * invN;
    double c02 = (s[6] - cnt * mx * mz) * invN;
    double c11 = (s[7] - cnt * my * my) * invN;
    double c12 = (s[8] - cnt * my * mz) * invN;
    double c22 = (s[9] - cnt * mz * mz) * invN;

    double qm = (c00 + c11 + c22) / 3.0;
    double p1 = c01*c01 + c02*c02 + c12*c12;
    double a0 = c00 - qm, a1 = c11 - qm, a2 = c22 - qm;
    double p2 = a0*a0 + a1*a1 + a2*a2 + 2.0*p1;
    double e_lo, e_mid, e_hi;
    if (p2 < 1e-32) {
        e_lo = e_mid = e_hi = qm;
    } else {
        double p = sqrt(p2 / 6.0);
        double inv = 1.0 / p;
        double b00 = a0*inv, b11 = a1*inv, b22 = a2*inv;
        double b01 = c01*inv, b02 = c02*inv, b12 = c12*inv;
        double detB = b00*(b11*b22 - b12*b12)
                    - b01*(b01*b22 - b12*b02)
                    + b02*(b01*b12 - b11*b02);
        double r = 0.5 * detB;
        r = fmin(1.0, fmax(-1.0, r));
        double phi = acos(r) / 3.0;
        double two_p = 2.0 * p;
        e_hi = qm + two_p * cos(phi);
        e_lo = qm + two_p * cos(phi + 2.0943951023931953);
        e_mid = 3.0 * qm - e_hi - e_lo;
    }
    float e0 = (float)e_lo, e1 = (float)e_mid, e2 = (float)e_hi;

    float t[4];
    #pragma unroll
    for (int o = 0; o < 4; ++o)
        t[o] = fmaxf(e0 * ew1[o*3+0] + e1 * ew1[o*3+1] +
                     e2 * ew1[o*3+2] + eb1[o], 0.f);
    bf16x4 ov;
    #pragma unroll
    for (int o = 0; o < 4; ++o) {
        float h = t[0]*ew2[o*4+0] + t[1]*ew2[o*4+1] +
                  t[2]*ew2[o*4+2] + t[3]*ew2[o*4+3] + eb2[o];
        ov[o] = f2h(h);
    }
    *(bf16x4*)&zinT[((size_t)b * N_PTS + i) * 192 + 160] = ov;
}

// ---------------------------------------------------------------------------
// h1 [B][128][N] f32 -> zinT [B][N][192] fp16 ch 0..127, zero ch 164..191.
// LDS 128x32 tile transpose. Grid: (N/32, B).
// ---------------------------------------------------------------------------
__global__ __launch_bounds__(256) void h1_transpose_kernel(
    const float* __restrict__ h1, short* __restrict__ zinT)
{
    const int b = blockIdx.y;
    const int n0 = blockIdx.x * 32;
    __shared__ float tile[128][33];
    #pragma unroll
    for (int it = 0; it < 16; ++it) {
        int idx = it * 256 + threadIdx.x;
        int c = idx >> 5, n = idx & 31;
        tile[c][n] = h1[((size_t)b * 128 + c) * N_PTS + n0 + n];
    }
    __syncthreads();
    #pragma unroll
    for (int it = 0; it < 16; ++it) {
        int idx = it * 256 + threadIdx.x;
        int c = idx & 127, n = idx >> 7;
        zinT[((size_t)b * N_PTS + n0 + n) * 192 + c] = f2h(tile[c][n]);
    }
    for (int idx = threadIdx.x; idx < 32 * 28; idx += 256) {
        int n = idx / 28, c = 164 + idx % 28;
        zinT[((size_t)b * N_PTS + n0 + n) * 192 + c] = 0;
    }
}

// ---------------------------------------------------------------------------
// h2_in [B][1024][N] f32 -> t_h2 [B][N][1024] fp16. Grid: (N/32, 8, B).
// ---------------------------------------------------------------------------
__global__ __launch_bounds__(256) void h2_transpose_kernel(
    const float* __restrict__ h2, short* __restrict__ t_h2)
{
    const int b = blockIdx.z;
    const int c0 = blockIdx.y * 128;
    const int n0 = blockIdx.x * 32;
    __shared__ float tile[128][33];
    #pragma unroll
    for (int it = 0; it < 16; ++it) {
        int idx = it * 256 + threadIdx.x;
        int c = idx >> 5, n = idx & 31;
        tile[c][n] = h2[((size_t)b * 1024 + c0 + c) * N_PTS + n0 + n];
    }
    __syncthreads();
    #pragma unroll
    for (int it = 0; it < 16; ++it) {
        int idx = it * 256 + threadIdx.x;
        int c = idx & 127, n = idx >> 7;
        t_h2[((size_t)b * N_PTS + n0 + n) * 1024 + c0 + c] = f2h(tile[c][n]);
    }
}

// ---------------------------------------------------------------------------
// xyz passthrough (f32)
// ---------------------------------------------------------------------------
__global__ __launch_bounds__(256) void xyz_out_kernel(
    const float* __restrict__ xyz, float* __restrict__ out)
{
    int idx = blockIdx.x * 256 + threadIdx.x;
    if (idx < BATCH * N_PTS * 3) out[idx] = xyz[idx];
}

// ---------------------------------------------------------------------------
// Weight f32 -> fp16, k-linear, zero-padded to [Mp][Kp]
// ---------------------------------------------------------------------------
__global__ __launch_bounds__(256) void conv_weight_kernel(
    const float* __restrict__ W, short* __restrict__ Wb,
    int M, int K, int Mp, int Kp)
{
    int id = blockIdx.x * 256 + threadIdx.x;
    if (id >= Mp * Kp) return;
    int mrow = id / Kp, k = id - mrow * Kp;
    float v = (mrow < M && k < K) ? W[(size_t)mrow * K + k] : 0.f;
    Wb[(size_t)mrow * Kp + k] = f2h(v);
}

// ---------------------------------------------------------------------------
// fp16 MFMA GEMM, k-contiguous X (XT: [B][N][Kp] fp16):
//   Y[b,m,n] = relu((sum_k W[m,k] XT[b,n,k] + bias)*scale + shift)
// 256 threads = 4 waves (2x2). W and X staged with IDENTICAL vector 16B
// pattern (no transpose, no scatter). Register double-buffer: one barrier
// per K-step, global loads for t+1 issued before compute(t).
// OUTT: fp16 transposed out YT[b][n][ostride] at channel offset (ptr pre-
// offset); else f32 [b][m][n] with batch stride ybs.
// Fragment reads use same bijection pi(g,s)=g*8+s on A and B (layout-safe).
// ---------------------------------------------------------------------------
template<int BM, int BN, bool OUTT>
__global__ __launch_bounds__(256) void mfma_gemm(
    const short* __restrict__ Wb, const short* __restrict__ XT,
    const float* __restrict__ bias, const float* __restrict__ scale,
    const float* __restrict__ shift, void* __restrict__ Yv,
    int M, int Kp, int ostride, size_t ybs)
{
    constexpr int LDW = 40;                    // padded LDS stride (shorts)
    constexpr int FM = BM / 32, FN = BN / 32;  // frags per wave
    constexpr int NCH = (BM + BN) * 4;         // 16B chunks per K-step
    constexpr int NREG = (NCH + 255) / 256;
    __shared__ __align__(16) short Wl[2][BM][LDW];
    __shared__ __align__(16) short Xl[2][BN][LDW];

    const int tid = threadIdx.x;
    const int lane = tid & 63, wave = tid >> 6;
    const int g = lane >> 4, r = lane & 15;
    const int wr = wave >> 1, wc = wave & 1;
    const int wm0 = wr * (BM / 2), wn0 = wc * (BN / 2);
    const int b = blockIdx.z;
    const int m0 = blockIdx.y * BM, n0 = blockIdx.x * BN;
    const int NT = Kp >> 5;

    f32x4 acc[FM][FN];
    #pragma unroll
    for (int i = 0; i < FM; ++i)
        #pragma unroll
        for (int jj = 0; jj < FN; ++jj)
            acc[i][jj] = (f32x4){0.f, 0.f, 0.f, 0.f};

    bf16x8 rg[NREG];

    auto load_regs = [&](int t) {
        #pragma unroll
        for (int u = 0; u < NREG; ++u) {
            int id = u * 256 + tid;
            if (id < NCH) {
                if (id < BM * 4) {
                    int m = id >> 2, c4 = id & 3;
                    rg[u] = *(const bf16x8*)&Wb[(size_t)(m0 + m) * Kp + (t << 5) + c4 * 8];
                } else {
                    int id2 = id - BM * 4;
                    int n = id2 >> 2, c4 = id2 & 3;
                    rg[u] = *(const bf16x8*)&XT[((size_t)b * N_PTS + n0 + n) * Kp + (t << 5) + c4 * 8];
                }
            }
        }
    };
    auto write_lds = [&](int nb) {
        #pragma unroll
        for (int u = 0; u < NREG; ++u) {
            int id = u * 256 + tid;
            if (id < NCH) {
                if (id < BM * 4) {
                    int m = id >> 2, c4 = id & 3;
                    *(bf16x8*)&Wl[nb][m][c4 * 8] = rg[u];
                } else {
                    int id2 = id - BM * 4;
                    int n = id2 >> 2, c4 = id2 & 3;
                    *(bf16x8*)&Xl[nb][n][c4 * 8] = rg[u];
                }
            }
        }
    };
    auto compute = [&](int cb) {
        #pragma unroll
        for (int fn = 0; fn < FN; ++fn) {
            bf16x8 bb = *(const bf16x8*)&Xl[cb][wn0 + fn * 16 + r][g * 8];
            #pragma unroll
            for (int fm = 0; fm < FM; ++fm) {
                bf16x8 a = *(const bf16x8*)&Wl[cb][wm0 + fm * 16 + r][g * 8];
                acc[fm][fn] = __builtin_amdgcn_mfma_f32_16x16x32_f16(
                    __builtin_bit_cast(f16x8, a),
                    __builtin_bit_cast(f16x8, bb),
                    acc[fm][fn], 0, 0, 0);
            }
        }
    };

    load_regs(0);
    write_lds(0);
    __syncthreads();
    for (int t = 0; t < NT; ++t) {
        int cb = t & 1;
        if (t + 1 < NT) load_regs(t + 1);
        compute(cb);
        if (t + 1 < NT) write_lds(cb ^ 1);   // other buffer: no hazard vs compute(cb)
        __syncthreads();
    }

    if constexpr (OUTT) {
        short* Y = (short*)Yv;
        #pragma unroll
        for (int fm = 0; fm < FM; ++fm) {
            int mb = m0 + wm0 + fm * 16 + g * 4;
            if (mb < M) {
                float4 b4 = *(const float4*)&bias[mb];
                float4 s4 = *(const float4*)&scale[mb];
                float4 h4 = *(const float4*)&shift[mb];
                #pragma unroll
                for (int fn = 0; fn < FN; ++fn) {
                    int n = n0 + wn0 + fn * 16 + r;
                    f32x4 a = acc[fm][fn];
                    bf16x4 o;
                    o[0] = f2h(fmaxf(fmaf(a[0] + b4.x, s4.x, h4.x), 0.f));
                    o[1] = f2h(fmaxf(fmaf(a[1] + b4.y, s4.y, h4.y), 0.f));
                    o[2] = f2h(fmaxf(fmaf(a[2] + b4.z, s4.z, h4.z), 0.f));
                    o[3] = f2h(fmaxf(fmaf(a[3] + b4.w, s4.w, h4.w), 0.f));
                    *(bf16x4*)&Y[((size_t)b * N_PTS + n) * ostride + mb] = o;
                }
            }
        }
    } else {
        float* Y = (float*)Yv;
        #pragma unroll
        for (int fm = 0; fm < FM; ++fm) {
            int mbase = m0 + wm0 + fm * 16 + g * 4;
            #pragma unroll
            for (int e = 0; e < 4; ++e) {
                int mm = mbase + e;
                if (mm >= M) continue;
                float bs = bias[mm], sc = scale[mm], sh = shift[mm];
                #pragma unroll
                for (int fn = 0; fn < FN; ++fn) {
                    int n = n0 + wn0 + fn * 16 + r;
                    float v = fmaxf(fmaf(acc[fm][fn][e] + bs, sc, sh), 0.f);
                    Y[(size_t)b * ybs + (size_t)mm * N_PTS + n] = v;
                }
            }
        }
    }
}

// ---------------------------------------------------------------------------
extern "C" void kernel_launch(void* const* d_in, const int* in_sizes, int n_in,
                              void* d_out, int out_size, void* d_ws, size_t ws_size,
                              hipStream_t stream)
{
    const float* xyz   = (const float*)d_in[0];
    const float* h1    = (const float*)d_in[1];
    const float* h2_in = (const float*)d_in[2];
    const float* dg_w1 = (const float*)d_in[3];
    const float* dg_b1 = (const float*)d_in[4];
    const float* dg_s1 = (const float*)d_in[5];
    const float* dg_t1 = (const float*)d_in[6];
    const float* dg_w2 = (const float*)d_in[7];
    const float* dg_b2 = (const float*)d_in[8];
    const float* dg_s2 = (const float*)d_in[9];
    const float* dg_t2 = (const float*)d_in[10];
    const float* dg_w3 = (const float*)d_in[11];
    const float* dg_b3 = (const float*)d_in[12];
    const float* dg_s3 = (const float*)d_in[13];
    const float* dg_t3 = (const float*)d_in[14];
    const float* ed_w1 = (const float*)d_in[15];
    const float* ed_b1 = (const float*)d_in[16];
    const float* ed_w2 = (const float*)d_in[17];
    const float* ed_b2 = (const float*)d_in[18];
    const float* w1 = (const float*)d_in[19];
    const float* b1 = (const float*)d_in[20];
    const float* s1 = (const float*)d_in[21];
    const float* t1 = (const float*)d_in[22];
    const float* w2 = (const float*)d_in[23];
    const float* b2 = (const float*)d_in[24];
    const float* s2 = (const float*)d_in[25];
    const float* t2 = (const float*)d_in[26];
    const float* w3 = (const float*)d_in[27];
    const float* b3 = (const float*)d_in[28];
    const float* s3 = (const float*)d_in[29];
    const float* t3 = (const float*)d_in[30];

    float* out = (float*)d_out;

    // workspace layout (bufB aliases t_h2, bufD aliases bufA)
    char* ws = (char*)d_ws;
    size_t off = 0;
    auto alloc = [&](size_t bytes) {
        char* p = ws + off;
        off += (bytes + 255) & ~(size_t)255;
        return p;
    };
    unsigned int* maxd2 = (unsigned int*)alloc(256);
    short* wb1  = (short*)alloc((size_t)256 * 1024 * 2);
    short* wb2  = (short*)alloc((size_t)64  * 256  * 2);
    short* wb3  = (short*)alloc((size_t)64  * 64   * 2);
    short* wbf1 = (short*)alloc((size_t)512 * 192  * 2);
    short* wbf2 = (short*)alloc((size_t)256 * 512  * 2);
    short* wbf3 = (short*)alloc((size_t)128 * 256  * 2);
    short* zinT = (short*)alloc((size_t)BATCH * N_PTS * 192 * 2);   // 6.3 MB
    short* t_h2 = (short*)alloc((size_t)BATCH * N_PTS * 1024 * 2);  // 33.5 MB
    short* bufA = (short*)alloc((size_t)BATCH * N_PTS * 256 * 2);   // 8.4 MB
    short* bufC = (short*)alloc((size_t)BATCH * N_PTS * 64 * 2);    // 2.1 MB
    float* pbuf = (float*)alloc((size_t)BATCH * JS * N_PTS * 10 * 4); // 5.2 MB
    short* bufB = t_h2;   // [B][N][512] fp16, 16.8 MB <= 33.5 (t_h2 dead after DG1)
    short* bufD = bufA;   // [B][N][256] fp16 (bufA dead after DG2)

    init_maxd2_kernel<<<1, 64, 0, stream>>>(maxd2);

    auto wconv = [&](const float* W, short* Wb, int M, int K, int Mp, int Kp) {
        conv_weight_kernel<<<(Mp * Kp + 255) / 256, 256, 0, stream>>>(W, Wb, M, K, Mp, Kp);
    };
    wconv(dg_w1, wb1, 256, 1024, 256, 1024);
    wconv(dg_w2, wb2, 64, 256, 64, 256);
    wconv(dg_w3, wb3, 32, 64, 64, 64);
    wconv(w1, wbf1, 512, 164, 512, 192);
    wconv(w2, wbf2, 256, 512, 256, 512);
    wconv(w3, wbf3, 128, 256, 128, 256);

    // eigen branch
    dim3 gsplit(N_PTS / 64, JS, BATCH);
    radius_max_kernel<<<gsplit, 256, 0, stream>>>(xyz, maxd2);
    eigen_accum_kernel<<<gsplit, 256, 0, stream>>>(xyz, maxd2, pbuf);
    eigen_finalize_kernel<<<(BATCH * N_PTS + 255) / 256, 256, 0, stream>>>(
        xyz, pbuf, ed_w1, ed_b1, ed_w2, ed_b2, zinT);

    // layout transposes
    h2_transpose_kernel<<<dim3(N_PTS / 32, 8, BATCH), 256, 0, stream>>>(h2_in, t_h2);
    h1_transpose_kernel<<<dim3(N_PTS / 32, BATCH), 256, 0, stream>>>(h1, zinT);
    xyz_out_kernel<<<(BATCH * N_PTS * 3 + 255) / 256, 256, 0, stream>>>(xyz, out);

    // GEMM chain (all X k-contiguous)
    // DG1: 1024 -> 256
    mfma_gemm<128, 64, true><<<dim3(N_PTS/64, 2, BATCH), 256, 0, stream>>>(
        wb1, t_h2, dg_b1, dg_s1, dg_t1, bufA, 256, 1024, 256, 0);
    // DG2: 256 -> 64
    mfma_gemm<64, 32, true><<<dim3(N_PTS/32, 1, BATCH), 256, 0, stream>>>(
        wb2, bufA, dg_b2, dg_s2, dg_t2, bufC, 64, 256, 64, 0);
    // DG3: 64 -> 32 (zinT ch 128..159)
    mfma_gemm<64, 32, true><<<dim3(N_PTS/32, 1, BATCH), 256, 0, stream>>>(
        wb3, bufC, dg_b3, dg_s3, dg_t3, zinT + 128, 32, 64, 192, 0);
    // F1: 192 -> 512
    mfma_gemm<128, 64, true><<<dim3(N_PTS/64, 4, BATCH), 256, 0, stream>>>(
        wbf1, zinT, b1, s1, t1, bufB, 512, 192, 512, 0);
    // F2: 512 -> 256
    mfma_gemm<128, 64, true><<<dim3(N_PTS/64, 2, BATCH), 256, 0, stream>>>(
        wbf2, bufB, b2, s2, t2, bufD, 256, 512, 256, 0);
    // F3: 256 -> 128 (f32 [b][m][n] into d_out after xyz)
    mfma_gemm<64, 64, false><<<dim3(N_PTS/64, 2, BATCH), 256, 0, stream>>>(
        wbf3, bufD, b3, s3, t3, out + (size_t)BATCH * N_PTS * 3, 128, 256, 0,
        (size_t)128 * N_PTS);
}